// Round 12
// baseline (57825.256 us; speedup 1.0000x reference)
//
#include <hip/hip_runtime.h>
#include <hip/hip_bf16.h>

typedef __bf16 bf16_t;
typedef __attribute__((ext_vector_type(8))) __bf16 bf16x8;
typedef __attribute__((ext_vector_type(4))) float f32x4;
typedef __attribute__((ext_vector_type(4))) unsigned u32x4;

#define T_STEPS 2048
#define HID 256
#define B_STRIDE 524288        // 2048*256: batch stride (f32 elements) in x and out
#define OUT_BASE 33554432ull   // 64*2048*256: start of h_n region in d_out (f32 elems)
#define HN_SZ 32768ull         // 2*64*256
#define RING_D 8
#define RING_SLICE 16384       // 64*256 bf16 per h1 timestep slice
#define GUARD_MAX (1<<16)

__device__ __forceinline__ float sigm(float x)  { return 1.f/(1.f+__expf(-x)); }
__device__ __forceinline__ float tanh_(float x) { return 2.f/(1.f+__expf(-2.f*x)) - 1.f; }

// poll counter until >= need; returns 1 on timeout (canary)
__device__ __forceinline__ int wait_cnt(const unsigned* p, unsigned need) {
  int guard = 0;
  while (__hip_atomic_load(p, __ATOMIC_RELAXED, __HIP_MEMORY_SCOPE_AGENT) < need) {
    __builtin_amdgcn_s_sleep(1);
    if (++guard > GUARD_MAX) return 1;
  }
  return 0;
}

// 8 contiguous f32 -> bf16x8 fragment (plain loads)
__device__ __forceinline__ bf16x8 cvt8(const float* p) {
  f32x4 a = *(const f32x4*)p;
  f32x4 b = *(const f32x4*)(p + 4);
  bf16x8 r;
  r[0]=(__bf16)a[0]; r[1]=(__bf16)a[1]; r[2]=(__bf16)a[2]; r[3]=(__bf16)a[3];
  r[4]=(__bf16)b[0]; r[5]=(__bf16)b[1]; r[6]=(__bf16)b[2]; r[7]=(__bf16)b[3];
  return r;
}

// 8 bf16 (4 u32) via agent-scope atomic loads (cross-XCD coherent)
__device__ __forceinline__ bf16x8 load_h8(const unsigned* b32, int idx) {
  u32x4 w4;
  w4[0] = __hip_atomic_load(b32 + idx + 0, __ATOMIC_RELAXED, __HIP_MEMORY_SCOPE_AGENT);
  w4[1] = __hip_atomic_load(b32 + idx + 1, __ATOMIC_RELAXED, __HIP_MEMORY_SCOPE_AGENT);
  w4[2] = __hip_atomic_load(b32 + idx + 2, __ATOMIC_RELAXED, __HIP_MEMORY_SCOPE_AGENT);
  w4[3] = __hip_atomic_load(b32 + idx + 3, __ATOMIC_RELAXED, __HIP_MEMORY_SCOPE_AGENT);
  return __builtin_bit_cast(bf16x8, w4);
}

// 8 f32 via agent-scope atomic loads -> bf16x8 fragment
__device__ __forceinline__ bf16x8 load_f8(const unsigned* b32 /* f32 bits */, int idx) {
  bf16x8 r;
  #pragma unroll
  for (int e = 0; e < 8; ++e) {
    unsigned u = __hip_atomic_load(b32 + idx + e, __ATOMIC_RELAXED, __HIP_MEMORY_SCOPE_AGENT);
    r[e] = (__bf16)__builtin_bit_cast(float, u);
  }
  return r;
}

// 128 blocks: l=(bid&7)>>2, g=bid&3 (16-batch group), c=bid>>3 (16 hid cols).
// Wave w = gate type (i,f,g,o). Weights persist in VGPRs as bf16 MFMA B-fragments.
// h1: bf16 in 8-deep ws ring. h2: f32 b-major in d_out out-region (fc in-place later).
// cnt[(l*T+t)*4+g]: one increment per chunk-block -> ==16 means (l,t,g) fully published.
__global__ __launch_bounds__(256) void lstm_pipe(
    const float* __restrict__ x,
    const float* __restrict__ w_ih, const float* __restrict__ w_hh,
    const float* __restrict__ b_ih, const float* __restrict__ b_hh,
    float* __restrict__ dout, bf16_t* __restrict__ ring,
    unsigned* __restrict__ cnt)
{
  const int tid  = threadIdx.x;
  const int lane = tid & 63;
  const int w    = tid >> 6;
  const int bid  = blockIdx.x;
  const int l    = (bid & 7) >> 2;
  const int g    = bid & 3;
  const int c    = bid >> 3;
  const int ln15 = lane & 15;
  const int kg   = lane >> 4;

  __shared__ float gl[4][16][16];
  __shared__ unsigned short hsh[16][16];
  __shared__ int badflag;
  if (tid == 0) badflag = 0;
  __syncthreads();

  // weight fragments (B layout: col=lane&15, k-slice ks, k=kg*8+e)
  const int row = 256*w + 16*c + ln15;
  const float* wihp = w_ih + ((size_t)l*1024 + row)*256 + kg*8;
  const float* whhp = w_hh + ((size_t)l*1024 + row)*256 + kg*8;
  bf16x8 wf[16];
  #pragma unroll
  for (int ks = 0; ks < 8; ++ks) {
    wf[ks]     = cvt8(wihp + 32*ks);
    wf[8 + ks] = cvt8(whhp + 32*ks);
  }
  const float bias = b_ih[(size_t)l*1024 + row] + b_hh[(size_t)l*1024 + row];

  const int ub = tid >> 4;
  const int uj = tid & 15;
  float c_state = 0.f;
  const int bg = 16*g;
  const int ab = bg + ln15;    // A row = batch (A layout: row=lane&15)

  for (int t = 0; t < T_STEPS; ++t) {
    bf16x8 axf[8];
    int to = 0;
    if (l == 0) {
      const float* xp = x + ((size_t)ab*T_STEPS + t)*HID + kg*8;   // x[b][t][:]
      #pragma unroll
      for (int ks = 0; ks < 8; ++ks) axf[ks] = cvt8(xp + 32*ks);
      if (tid == 0  && t > 0)       to = wait_cnt(&cnt[(size_t)(t-1)*4 + g], 16);
      if (tid == 64 && t >= RING_D) to = wait_cnt(&cnt[(size_t)(T_STEPS + t-RING_D)*4 + g], 16);
    } else {
      if (tid == 0)                 to = wait_cnt(&cnt[(size_t)t*4 + g], 16);           // h1[t]
      if (tid == 64 && t > 0)       to = wait_cnt(&cnt[(size_t)(T_STEPS + t-1)*4 + g], 16); // h2[t-1]
    }
    if (to) badflag = 1;
    __syncthreads();
    __threadfence();   // acquire side

    if (l == 1) {      // x-part = h1[t] (bf16 ring)
      const unsigned* xb32 = (const unsigned*)(ring + (size_t)(t & 7)*RING_SLICE + (size_t)ab*HID);
      #pragma unroll
      for (int ks = 0; ks < 8; ++ks) axf[ks] = load_h8(xb32, kg*4 + 16*ks);
    }

    f32x4 accx = {0.f,0.f,0.f,0.f};
    f32x4 acch = {0.f,0.f,0.f,0.f};
    if (t > 0) {
      bf16x8 ahf[8];
      if (l == 0) {
        const unsigned* hb32 = (const unsigned*)(ring + (size_t)((t-1) & 7)*RING_SLICE + (size_t)ab*HID);
        #pragma unroll
        for (int ks = 0; ks < 8; ++ks) ahf[ks] = load_h8(hb32, kg*4 + 16*ks);
      } else {
        const unsigned* hb32 = (const unsigned*)(dout + (size_t)ab*B_STRIDE + (size_t)(t-1)*HID);
        #pragma unroll
        for (int ks = 0; ks < 8; ++ks) ahf[ks] = load_f8(hb32, kg*8 + 32*ks);
      }
      #pragma unroll
      for (int ks = 0; ks < 8; ++ks) {
        accx = __builtin_amdgcn_mfma_f32_16x16x32_bf16(axf[ks], wf[ks],   accx, 0,0,0);
        acch = __builtin_amdgcn_mfma_f32_16x16x32_bf16(ahf[ks], wf[8+ks], acch, 0,0,0);
      }
    } else {
      #pragma unroll
      for (int ks = 0; ks < 8; ++ks)
        accx = __builtin_amdgcn_mfma_f32_16x16x32_bf16(axf[ks], wf[ks], accx, 0,0,0);
    }

    // D layout: col j = lane&15, row b = kg*4+r (m89-verified)
    #pragma unroll
    for (int r = 0; r < 4; ++r) {
      float v = accx[r] + acch[r] + bias;
      gl[w][kg*4 + r][ln15] = (w == 2) ? tanh_(v) : sigm(v);
    }
    __syncthreads();

    float iv = gl[0][ub][uj], fv = gl[1][ub][uj], gv = gl[2][ub][uj], ov = gl[3][ub][uj];
    c_state = fv * c_state + iv * gv;
    float h = ov * tanh_(c_state);
    if (badflag) h = 7.0f;            // canary
    if (t == T_STEPS-1) {
      size_t o = OUT_BASE + (size_t)l*16384 + (size_t)(bg+ub)*256 + 16*c + uj;
      dout[o]         = h;             // h_n (f32)
      dout[o + HN_SZ] = c_state;       // c_n (f32)
    }

    // ---- publish h ----
    if (l == 0) {
      bf16_t hb = (bf16_t)h;
      hsh[ub][uj] = __builtin_bit_cast(unsigned short, hb);
      __syncthreads();
      if (tid < 128) {
        int b8 = tid >> 3, jj = tid & 7;
        unsigned vv = ((const unsigned*)hsh)[tid];
        unsigned* dst32 = (unsigned*)(ring + (size_t)(t & 7)*RING_SLICE
                                           + (size_t)(bg+b8)*HID + 16*c) + jj;
        __hip_atomic_store(dst32, vv, __ATOMIC_RELAXED, __HIP_MEMORY_SCOPE_AGENT);
      }
    } else {
      // h2 f32 b-major into d_out out-region; one store per thread
      unsigned* dst32 = (unsigned*)(dout + (size_t)(bg+ub)*B_STRIDE + (size_t)t*HID + 16*c + uj);
      __hip_atomic_store(dst32, __builtin_bit_cast(unsigned, h),
                         __ATOMIC_RELAXED, __HIP_MEMORY_SCOPE_AGENT);
      __syncthreads();
    }
    __threadfence();   // release side
    __syncthreads();
    if (tid == 0)
      __hip_atomic_fetch_add(&cnt[(size_t)(l*T_STEPS + t)*4 + g], 1u,
                             __ATOMIC_RELEASE, __HIP_MEMORY_SCOPE_AGENT);
  }
}

// In-place FC+PReLU over f32 d_out: wave reads its 16 token rows (h2) into bf16
// fragments, then overwrites the same rows with the FC output (f32).
__global__ __launch_bounds__(256) void fc_kernel(
    const float* __restrict__ w_fc, const float* __restrict__ b_fc,
    const float* __restrict__ pa, float* __restrict__ dout)
{
  const int tid  = threadIdx.x;
  const int lane = tid & 63;
  const int wv   = tid >> 6;
  const int ln15 = lane & 15;
  const int kg   = lane >> 4;
  const int tokbase = blockIdx.x*64 + wv*16;   // token = t*64 + b
  const int bb0 = tokbase & 63;
  const int tt0 = tokbase >> 6;
  const float a = pa[0];

  bf16x8 af[8];
  const float* ap = dout + (size_t)(bb0 + ln15)*B_STRIDE + (size_t)tt0*HID + kg*8;
  #pragma unroll
  for (int ks = 0; ks < 8; ++ks) af[ks] = cvt8(ap + 32*ks);

  for (int nt = 0; nt < 16; ++nt) {
    const float* bp = w_fc + (size_t)(nt*16 + ln15)*256 + kg*8;
    f32x4 acc = {0.f,0.f,0.f,0.f};
    #pragma unroll
    for (int ks = 0; ks < 8; ++ks) {
      bf16x8 bfv = cvt8(bp + 32*ks);
      acc = __builtin_amdgcn_mfma_f32_16x16x32_bf16(af[ks], bfv, acc, 0,0,0);
    }
    float bias = b_fc[nt*16 + ln15];
    #pragma unroll
    for (int r = 0; r < 4; ++r) {
      float v = acc[r] + bias;
      v = (v >= 0.f) ? v : a*v;
      int b = bb0 + kg*4 + r;
      dout[(size_t)b*B_STRIDE + (size_t)tt0*HID + nt*16 + ln15] = v;
    }
  }
}

extern "C" void kernel_launch(void* const* d_in, const int* in_sizes, int n_in,
                              void* d_out, int out_size, void* d_ws, size_t ws_size,
                              hipStream_t stream) {
  const float* x    = (const float*)d_in[0];
  const float* w_ih = (const float*)d_in[1];
  const float* w_hh = (const float*)d_in[2];
  const float* b_ih = (const float*)d_in[3];
  const float* b_hh = (const float*)d_in[4];
  const float* w_fc = (const float*)d_in[5];
  const float* b_fc = (const float*)d_in[6];
  const float* pa   = (const float*)d_in[7];
  float* dout = (float*)d_out;                 // f32: reference output dtype

  unsigned* cnt  = (unsigned*)d_ws;                      // 64 KiB: 2*2048*4 u32
  bf16_t*   ring = (bf16_t*)((char*)d_ws + 65536);       // 256 KiB: 8 h1 slices

  hipMemsetAsync(cnt, 0, 2ull*T_STEPS*4*sizeof(unsigned), stream);
  lstm_pipe<<<128, 256, 0, stream>>>(x, w_ih, w_hh, b_ih, b_hh, dout, ring, cnt);
  fc_kernel<<<2048, 256, 0, stream>>>(w_fc, b_fc, pa, dout);
}